// Round 6
// baseline (485.650 us; speedup 1.0000x reference)
//
#include <hip/hip_runtime.h>
#include <math.h>

#pragma clang fp contract(off)

#define LL 4096
#define FF 128
#define NB 32
#define BASE 16
#define NBLK (LL / BASE)    // 256 level-0 tiles
#define NOB  (NBLK / BASE)  // 16 level-1 tiles

__device__ __forceinline__ float sani(float v) {
    return (fabsf(v) <= 3.0e38f) ? v : 0.0f;
}

// bit-exact np window math: mean=(dA-dB)/w; m2=(qA-qB)/w; var=max(m2-mean^2,0);
// sd=sqrt(var+eps); nz=(xc-mean)/sd; return wv*nz.  All RN, no contraction.
__device__ __forceinline__ float wterm(float dA, float dB, float qA, float qB,
                                       float xc, float wf, float wv) {
    const float mean = __fdiv_rn(__fsub_rn(dA, dB), wf);
    const float m2   = __fdiv_rn(__fsub_rn(qA, qB), wf);
    const float var  = fmaxf(__fsub_rn(m2, __fmul_rn(mean, mean)), 0.0f);
    const float sd   = __fsqrt_rn(__fadd_rn(var, 1e-5f));
    const float nz   = __fdiv_rn(__fsub_rn(xc, mean), sd);
    return __fmul_rn(wv, nz);
}

// One block per (b,f) column. Cumsum realization = XLA ReduceWindowRewriter
// two-level tiled scan, base_length=16:
//   s0: left-to-right scan within each 16-tile (values == running sequential)
//   T0[B] = tile totals (256) -> recursively: s1 within 16-tiles of T0,
//   T1[16] totals -> S2 = seq scan of T1;  scan1[B] = s1_B (+ S2[ob-1] if ob>0)
//   cs[j] = s0_j (+ scan1[B-1] if B>0)    -- one composing RN add per element.
__global__ __launch_bounds__(256) void fan_blocked(const float* __restrict__ x,
                                                   const float* __restrict__ w,
                                                   float* __restrict__ out) {
    __shared__ float2 V[LL];      // 32 KB: (cs, cs2) values
    __shared__ float2 T0[NBLK];   // 2 KB
    __shared__ float2 T1[NOB];
    __shared__ float2 S2[NOB];

    const int col = blockIdx.x;
    const int f   = col & (FF - 1);
    const int b   = col >> 7;
    const int tid = (int)threadIdx.x;

    const float* xcol = x   + (size_t)b * LL * FF + f;
    float*       ocol = out + (size_t)b * LL * FF + f;

    // load + elementwise square (RN)
    for (int l = tid; l < LL; l += 256) {
        const float v = sani(xcol[(size_t)l * FF]);
        V[l] = make_float2(v, __fmul_rn(v, v));
    }
    __syncthreads();

    // level 0: sequential scan within each 16-tile; thread tid owns tile tid
    {
        const int base = tid * BASE;
        float cs = V[base].x, cs2 = V[base].y;   // first elem: 0+v = v exact
        for (int u = 1; u < BASE; ++u) {
            const float2 e = V[base + u];
            cs  = __fadd_rn(cs,  e.x);
            cs2 = __fadd_rn(cs2, e.y);
            V[base + u] = make_float2(cs, cs2);
        }
        T0[tid] = make_float2(cs, cs2);
    }
    __syncthreads();

    // level 1: sequential scan within each 16-tile of T0 (in place)
    if (tid < NOB) {
        const int base = tid * BASE;
        float cs = T0[base].x, cs2 = T0[base].y;
        for (int u = 1; u < BASE; ++u) {
            const float2 e = T0[base + u];
            cs  = __fadd_rn(cs,  e.x);
            cs2 = __fadd_rn(cs2, e.y);
            T0[base + u] = make_float2(cs, cs2);
        }
        T1[tid] = make_float2(cs, cs2);
    }
    __syncthreads();

    // level 2: sequential scan of the 16 level-1 totals
    if (tid == 0) {
        float cs = T1[0].x, cs2 = T1[0].y;
        S2[0] = T1[0];
        for (int o = 1; o < NOB; ++o) {
            cs  = __fadd_rn(cs,  T1[o].x);
            cs2 = __fadd_rn(cs2, T1[o].y);
            S2[o] = make_float2(cs, cs2);
        }
    }
    __syncthreads();

    // compose: V[j] (tile B>0) += scan1[B-1], where
    // scan1[B] = T0s[B]            (B in outer-tile 0)
    //          = RN(T0s[B]+S2[ob-1]) otherwise      (T0 now holds s1 in place)
    {
        const int blk = tid;
        if (blk > 0) {
            const int B  = blk - 1;
            const int ob = B >> 4;
            float2 P = T0[B];
            if (ob > 0) {
                const float2 s2 = S2[ob - 1];
                P = make_float2(__fadd_rn(P.x, s2.x), __fadd_rn(P.y, s2.y));
            }
            const int base = blk * BASE;
            for (int u = 0; u < BASE; ++u) {
                const float2 s = V[base + u];
                V[base + u] = make_float2(__fadd_rn(s.x, P.x), __fadd_rn(s.y, P.y));
            }
        }
    }
    __syncthreads();
    // V[j] = inclusive cs over first j+1 elems; cs_arr[j] = V[j-1], cs_arr[0]=0.

    // softmax over 3 weights (uniform)
    const float w0 = w[0], w1 = w[1], w2 = w[2];
    const float mx = fmaxf(w0, fmaxf(w1, w2));
    const float e0 = expf(w0 - mx), e1 = expf(w1 - mx), e2 = expf(w2 - mx);
    const float s  = e0 + e1 + e2;
    const float ws0 = e0 / s, ws1 = e1 / s, ws2 = e2 / s;

    // window phase (verified in r3-r5)
    auto P = [&](int j) -> float2 {
        if (j <= 0) return make_float2(0.0f, 0.0f);
        int idx = j - 1; if (idx > LL - 1) idx = LL - 1;
        return V[idx];
    };
    for (int l = tid; l < LL; l += 256) {
        const float xc = sani(xcol[(size_t)l * FF]);
        const float2 A5  = P(l + 3),  B5  = P(l - 2);
        const float2 A10 = P(l + 5),  B10 = P(l - 5);
        const float2 A20 = P(l + 10), B20 = P(l - 10);
        const float g5  = (l >= 2  && l <= LL - 3)  ? ws0 : 0.0f;
        const float g10 = (l >= 5  && l <= LL - 5)  ? ws1 : 0.0f;
        const float g20 = (l >= 10 && l <= LL - 10) ? ws2 : 0.0f;
        float o = wterm(A5.x,  B5.x,  A5.y,  B5.y,  xc, 5.0f,  g5);
        o = __fadd_rn(o, wterm(A10.x, B10.x, A10.y, B10.y, xc, 10.0f, g10));
        o = __fadd_rn(o, wterm(A20.x, B20.x, A20.y, B20.y, xc, 20.0f, g20));
        ocol[(size_t)l * FF] = o;
    }
}

extern "C" void kernel_launch(void* const* d_in, const int* in_sizes, int n_in,
                              void* d_out, int out_size, void* d_ws, size_t ws_size,
                              hipStream_t stream) {
    const float* x = (const float*)d_in[0];
    const float* w = (const float*)d_in[1];
    float* out     = (float*)d_out;

    fan_blocked<<<dim3(NB * FF), dim3(256), 0, stream>>>(x, w, out);
}

// Round 7
// 106.874 us; speedup vs baseline: 4.5441x; 4.5441x over previous
//
#include <hip/hip_runtime.h>
#include <math.h>

#pragma clang fp contract(off)

#define LL 4096
#define FF 128
#define NB 32
#define BASE 16
#define NBLK 256            // tiles per column
#define NOB 16

__device__ __forceinline__ float sani(float v) {
    return (fabsf(v) <= 3.0e38f) ? v : 0.0f;
}

// bit-exact np window math (verified r6). All RN, no contraction.
__device__ __forceinline__ float wterm(float dA, float dB, float qA, float qB,
                                       float xc, float wf, float wv) {
    const float mean = __fdiv_rn(__fsub_rn(dA, dB), wf);
    const float m2   = __fdiv_rn(__fsub_rn(qA, qB), wf);
    const float var  = fmaxf(__fsub_rn(m2, __fmul_rn(mean, mean)), 0.0f);
    const float sd   = __fsqrt_rn(__fadd_rn(var, 1e-5f));
    const float nz   = __fdiv_rn(__fsub_rn(xc, mean), sd);
    return __fmul_rn(wv, nz);
}

// ---------- K1: per-tile sequential totals (level-0 tails) ----------
__global__ __launch_bounds__(256) void k_tiles(const float* __restrict__ x,
                                               float2* __restrict__ T0) {
    __shared__ float xs[32 * FF];        // 16 KB
    const int bid  = blockIdx.x;         // 32 b x 128 tile-pairs
    const int pair = bid & 127;
    const int b    = bid >> 7;
    const int tid  = (int)threadIdx.x;
    const float* xb = x + ((size_t)b * LL + (size_t)pair * 32) * FF;
    for (int i = tid; i < 32 * FF; i += 256) xs[i] = sani(xb[i]);
    __syncthreads();
    const int f = tid & 127, t = tid >> 7;       // t in 0..1
    const int blk = pair * 2 + t;
    float cs, cs2;
    {
        const float v = xs[(t * 16) * FF + f];
        cs = v; cs2 = __fmul_rn(v, v);
    }
#pragma unroll
    for (int u = 1; u < 16; ++u) {
        const float v = xs[(t * 16 + u) * FF + f];
        cs  = __fadd_rn(cs,  v);
        cs2 = __fadd_rn(cs2, __fmul_rn(v, v));
    }
    T0[((size_t)b * NBLK + blk) * FF + f] = make_float2(cs, cs2);
}

// ---------- K2: per-column levels 1+2 scan -> per-tile prefix P ----------
// s1: in-place scan within 16-groups of T0; S2: seq scan of group totals;
// P[blk] = blk==0 ? 0 : (blk-1 < 16 ? s1[blk-1] : RN(s1[blk-1] + S2[(blk-1)>>4 - 1]))
__global__ __launch_bounds__(64) void k_prefix(const float2* __restrict__ T0,
                                               float2* __restrict__ P) {
    const int bid = blockIdx.x;          // 64 = 32 b x 2 f-halves
    const int fh = bid & 1, b = bid >> 1;
    const int f  = fh * 64 + (int)threadIdx.x;
    const float2* t0c = T0 + (size_t)b * NBLK * FF + f;
    float2*       pc  = P  + (size_t)b * NBLK * FF + f;
    pc[0] = make_float2(0.0f, 0.0f);
    float S2x = 0.0f, S2y = 0.0f;        // S2 over completed groups
    for (int g = 0; g < NOB; ++g) {
        float s1x = 0.0f, s1y = 0.0f;
#pragma unroll
        for (int i = 0; i < 16; ++i) {
            const int B = g * 16 + i;
            const float2 t = t0c[(size_t)B * FF];
            if (i == 0) { s1x = t.x; s1y = t.y; }
            else        { s1x = __fadd_rn(s1x, t.x); s1y = __fadd_rn(s1y, t.y); }
            if (B < NBLK - 1) {
                float px = s1x, py = s1y;
                if (g > 0) { px = __fadd_rn(s1x, S2x); py = __fadd_rn(s1y, S2y); }
                pc[(size_t)(B + 1) * FF] = make_float2(px, py);
            }
        }
        if (g == 0) { S2x = s1x; S2y = s1y; }
        else        { S2x = __fadd_rn(S2x, s1x); S2y = __fadd_rn(S2y, s1y); }
    }
}

// ---------- K3: reconstruct V per 6-tile slab in LDS + window phase ----------
__global__ __launch_bounds__(256) void k_win(const float* __restrict__ x,
                                             const float* __restrict__ w,
                                             const float2* __restrict__ P,
                                             float* __restrict__ out) {
    __shared__ float Vcs[96 * 64];       // 24 KB (SoA: 2-way-free banks)
    __shared__ float Vq [96 * 64];       // 24 KB
    const int bid = blockIdx.x;          // 32 b x 64 tq x 2 fh
    const int fh = bid & 1;
    const int tq = (bid >> 1) & 63;
    const int b  = bid >> 7;
    const int tid = (int)threadIdx.x;
    const int ls0 = tq * 64 - 16;        // global l of staged slot 0

    // stage V for tiles tq*4-1 .. tq*4+4 (identical RN chain + per-elem P add)
    for (int task = tid; task < 384; task += 256) {
        const int k = task >> 6, f_loc = task & 63;
        const int f = fh * 64 + f_loc;
        const int tile = tq * 4 - 1 + k;
        if (tile < 0 || tile >= NBLK) {
#pragma unroll
            for (int u = 0; u < 16; ++u) {
                Vcs[(k * 16 + u) * 64 + f_loc] = 0.0f;
                Vq [(k * 16 + u) * 64 + f_loc] = 0.0f;
            }
        } else {
            const float2 Pp = P[((size_t)b * NBLK + tile) * FF + f];
            const float* xt = x + ((size_t)b * LL + (size_t)tile * 16) * FF + f;
            float cs = 0.0f, cs2 = 0.0f;
#pragma unroll
            for (int u = 0; u < 16; ++u) {
                const float v = sani(xt[(size_t)u * FF]);
                if (u == 0) { cs = v; cs2 = __fmul_rn(v, v); }
                else { cs = __fadd_rn(cs, v); cs2 = __fadd_rn(cs2, __fmul_rn(v, v)); }
                Vcs[(k * 16 + u) * 64 + f_loc] = __fadd_rn(cs,  Pp.x);
                Vq [(k * 16 + u) * 64 + f_loc] = __fadd_rn(cs2, Pp.y);
            }
        }
    }
    __syncthreads();

    // softmax over 3 weights (uniform)
    const float w0 = w[0], w1 = w[1], w2 = w[2];
    const float mx = fmaxf(w0, fmaxf(w1, w2));
    const float e0 = expf(w0 - mx), e1 = expf(w1 - mx), e2 = expf(w2 - mx);
    const float s  = e0 + e1 + e2;
    const float ws0 = e0 / s, ws1 = e1 / s, ws2 = e2 / s;

    const int kt = tid >> 6, f_loc = tid & 63;
    const int f = fh * 64 + f_loc;
    const int tile = tq * 4 + kt;
    const float* xc0 = x   + ((size_t)b * LL + (size_t)tile * 16) * FF + f;
    float*       oc0 = out + ((size_t)b * LL + (size_t)tile * 16) * FF + f;

    auto PVx = [&](int j) -> float {
        if (j <= 0) return 0.0f;
        const int idx = (j > LL ? LL : j) - 1;
        return Vcs[(idx - ls0) * 64 + f_loc];
    };
    auto PVy = [&](int j) -> float {
        if (j <= 0) return 0.0f;
        const int idx = (j > LL ? LL : j) - 1;
        return Vq[(idx - ls0) * 64 + f_loc];
    };

#pragma unroll
    for (int u = 0; u < 16; ++u) {
        const int l = tile * 16 + u;
        const float xc = sani(xc0[(size_t)u * FF]);
        const float g5  = (l >= 2  && l <= LL - 3)  ? ws0 : 0.0f;
        const float g10 = (l >= 5  && l <= LL - 5)  ? ws1 : 0.0f;
        const float g20 = (l >= 10 && l <= LL - 10) ? ws2 : 0.0f;
        float o = wterm(PVx(l + 3),  PVx(l - 2),  PVy(l + 3),  PVy(l - 2),  xc, 5.0f,  g5);
        o = __fadd_rn(o, wterm(PVx(l + 5),  PVx(l - 5),  PVy(l + 5),  PVy(l - 5),  xc, 10.0f, g10));
        o = __fadd_rn(o, wterm(PVx(l + 10), PVx(l - 10), PVy(l + 10), PVy(l - 10), xc, 20.0f, g20));
        oc0[(size_t)u * FF] = o;
    }
}

// ---------- fallback: verified single-kernel r6 (if ws too small) ----------
__global__ __launch_bounds__(256) void fan_blocked(const float* __restrict__ x,
                                                   const float* __restrict__ w,
                                                   float* __restrict__ out) {
    __shared__ float2 V[LL];
    __shared__ float2 T0s[NBLK];
    __shared__ float2 T1[NOB];
    __shared__ float2 S2[NOB];
    const int col = blockIdx.x;
    const int f   = col & (FF - 1);
    const int b   = col >> 7;
    const int tid = (int)threadIdx.x;
    const float* xcol = x   + (size_t)b * LL * FF + f;
    float*       ocol = out + (size_t)b * LL * FF + f;
    for (int l = tid; l < LL; l += 256) {
        const float v = sani(xcol[(size_t)l * FF]);
        V[l] = make_float2(v, __fmul_rn(v, v));
    }
    __syncthreads();
    {
        const int base = tid * BASE;
        float cs = V[base].x, cs2 = V[base].y;
        for (int u = 1; u < BASE; ++u) {
            const float2 e = V[base + u];
            cs = __fadd_rn(cs, e.x); cs2 = __fadd_rn(cs2, e.y);
            V[base + u] = make_float2(cs, cs2);
        }
        T0s[tid] = make_float2(cs, cs2);
    }
    __syncthreads();
    if (tid < NOB) {
        const int base = tid * BASE;
        float cs = T0s[base].x, cs2 = T0s[base].y;
        for (int u = 1; u < BASE; ++u) {
            const float2 e = T0s[base + u];
            cs = __fadd_rn(cs, e.x); cs2 = __fadd_rn(cs2, e.y);
            T0s[base + u] = make_float2(cs, cs2);
        }
        T1[tid] = make_float2(cs, cs2);
    }
    __syncthreads();
    if (tid == 0) {
        float cs = T1[0].x, cs2 = T1[0].y;
        S2[0] = T1[0];
        for (int o = 1; o < NOB; ++o) {
            cs = __fadd_rn(cs, T1[o].x); cs2 = __fadd_rn(cs2, T1[o].y);
            S2[o] = make_float2(cs, cs2);
        }
    }
    __syncthreads();
    {
        const int blk = tid;
        if (blk > 0) {
            const int B = blk - 1, ob = B >> 4;
            float2 Pp = T0s[B];
            if (ob > 0) {
                const float2 s2 = S2[ob - 1];
                Pp = make_float2(__fadd_rn(Pp.x, s2.x), __fadd_rn(Pp.y, s2.y));
            }
            const int base = blk * BASE;
            for (int u = 0; u < BASE; ++u) {
                const float2 sv = V[base + u];
                V[base + u] = make_float2(__fadd_rn(sv.x, Pp.x), __fadd_rn(sv.y, Pp.y));
            }
        }
    }
    __syncthreads();
    const float w0 = w[0], w1 = w[1], w2 = w[2];
    const float mx = fmaxf(w0, fmaxf(w1, w2));
    const float e0 = expf(w0 - mx), e1 = expf(w1 - mx), e2 = expf(w2 - mx);
    const float s  = e0 + e1 + e2;
    const float ws0 = e0 / s, ws1 = e1 / s, ws2 = e2 / s;
    auto PV = [&](int j) -> float2 {
        if (j <= 0) return make_float2(0.0f, 0.0f);
        int idx = j - 1; if (idx > LL - 1) idx = LL - 1;
        return V[idx];
    };
    for (int l = tid; l < LL; l += 256) {
        const float xc = sani(xcol[(size_t)l * FF]);
        const float2 A5 = PV(l + 3), B5 = PV(l - 2);
        const float2 A10 = PV(l + 5), B10 = PV(l - 5);
        const float2 A20 = PV(l + 10), B20 = PV(l - 10);
        const float g5  = (l >= 2  && l <= LL - 3)  ? ws0 : 0.0f;
        const float g10 = (l >= 5  && l <= LL - 5)  ? ws1 : 0.0f;
        const float g20 = (l >= 10 && l <= LL - 10) ? ws2 : 0.0f;
        float o = wterm(A5.x, B5.x, A5.y, B5.y, xc, 5.0f, g5);
        o = __fadd_rn(o, wterm(A10.x, B10.x, A10.y, B10.y, xc, 10.0f, g10));
        o = __fadd_rn(o, wterm(A20.x, B20.x, A20.y, B20.y, xc, 20.0f, g20));
        ocol[(size_t)l * FF] = o;
    }
}

extern "C" void kernel_launch(void* const* d_in, const int* in_sizes, int n_in,
                              void* d_out, int out_size, void* d_ws, size_t ws_size,
                              hipStream_t stream) {
    const float* x = (const float*)d_in[0];
    const float* w = (const float*)d_in[1];
    float* out     = (float*)d_out;

    const size_t t0_bytes = (size_t)NB * NBLK * FF * sizeof(float2);   // 8 MiB
    if (ws_size >= 2 * t0_bytes) {
        float2* T0 = (float2*)d_ws;
        float2* P  = (float2*)((char*)d_ws + t0_bytes);
        k_tiles <<<dim3(NB * 128), dim3(256), 0, stream>>>(x, T0);
        k_prefix<<<dim3(NB * 2),   dim3(64),  0, stream>>>(T0, P);
        k_win   <<<dim3(NB * 64 * 2), dim3(256), 0, stream>>>(x, w, P, out);
    } else {
        fan_blocked<<<dim3(NB * FF), dim3(256), 0, stream>>>(x, w, out);
    }
}

// Round 8
// 77.266 us; speedup vs baseline: 6.2854x; 1.3832x over previous
//
#include <hip/hip_runtime.h>
#include <math.h>

#pragma clang fp contract(off)

#define LL 4096
#define FF 128
#define NB 32
#define BASE 16
#define NBLK 256            // tiles per column
#define NOB 16

__device__ __forceinline__ float sani(float v) {
    return (fabsf(v) <= 3.0e38f) ? v : 0.0f;
}

// ---------- K1: per-tile sequential totals (level-0 tails) ----------
__global__ __launch_bounds__(256) void k_tiles(const float* __restrict__ x,
                                               float2* __restrict__ T0) {
    __shared__ float xs[32 * FF];        // 16 KB
    const int bid  = blockIdx.x;         // 32 b x 128 tile-pairs
    const int pair = bid & 127;
    const int b    = bid >> 7;
    const int tid  = (int)threadIdx.x;
    const float* xb = x + ((size_t)b * LL + (size_t)pair * 32) * FF;
    for (int i = tid; i < 32 * FF; i += 256) xs[i] = sani(xb[i]);
    __syncthreads();
    const int f = tid & 127, t = tid >> 7;       // t in 0..1
    const int blk = pair * 2 + t;
    float cs, cs2;
    {
        const float v = xs[(t * 16) * FF + f];
        cs = v; cs2 = __fmul_rn(v, v);
    }
#pragma unroll
    for (int u = 1; u < 16; ++u) {
        const float v = xs[(t * 16 + u) * FF + f];
        cs  = __fadd_rn(cs,  v);
        cs2 = __fadd_rn(cs2, __fmul_rn(v, v));
    }
    T0[((size_t)b * NBLK + blk) * FF + f] = make_float2(cs, cs2);
}

// ---------- K2: per-column levels 1+2 scan -> per-tile prefix P ----------
__global__ __launch_bounds__(64) void k_prefix(const float2* __restrict__ T0,
                                               float2* __restrict__ P) {
    const int bid = blockIdx.x;          // 64 = 32 b x 2 f-halves
    const int fh = bid & 1, b = bid >> 1;
    const int f  = fh * 64 + (int)threadIdx.x;
    const float2* t0c = T0 + (size_t)b * NBLK * FF + f;
    float2*       pc  = P  + (size_t)b * NBLK * FF + f;
    pc[0] = make_float2(0.0f, 0.0f);
    float S2x = 0.0f, S2y = 0.0f;        // S2 over completed groups
    for (int g = 0; g < NOB; ++g) {
        float s1x = 0.0f, s1y = 0.0f;
#pragma unroll
        for (int i = 0; i < 16; ++i) {
            const int B = g * 16 + i;
            const float2 t = t0c[(size_t)B * FF];
            if (i == 0) { s1x = t.x; s1y = t.y; }
            else        { s1x = __fadd_rn(s1x, t.x); s1y = __fadd_rn(s1y, t.y); }
            if (B < NBLK - 1) {
                float px = s1x, py = s1y;
                if (g > 0) { px = __fadd_rn(s1x, S2x); py = __fadd_rn(s1y, S2y); }
                pc[(size_t)(B + 1) * FF] = make_float2(px, py);
            }
        }
        if (g == 0) { S2x = s1x; S2y = s1y; }
        else        { S2x = __fadd_rn(S2x, s1x); S2y = __fadd_rn(S2y, s1y); }
    }
}

// ---------- K3: reconstruct V per 6-tile slab in LDS + window phase ----------
__global__ __launch_bounds__(256) void k_win(const float* __restrict__ x,
                                             const float* __restrict__ w,
                                             const float2* __restrict__ P,
                                             float* __restrict__ out) {
    __shared__ float2 V2[96 * 64];       // 48 KB; lane stride 8B = 2-way (free)
    const int bid = blockIdx.x;          // 32 b x 64 tq x 2 fh
    const int fh = bid & 1;
    const int tq = (bid >> 1) & 63;
    const int b  = bid >> 7;
    const int tid = (int)threadIdx.x;
    const int ls0 = tq * 64 - 16;        // global l of staged slot 0

    // stage V for tiles tq*4-1 .. tq*4+4 — identical RN chain to r7 (realization-locked)
    for (int task = tid; task < 384; task += 256) {
        const int k = task >> 6, f_loc = task & 63;
        const int f = fh * 64 + f_loc;
        const int tile = tq * 4 - 1 + k;
        if (tile < 0 || tile >= NBLK) {
#pragma unroll
            for (int u = 0; u < 16; ++u)
                V2[(k * 16 + u) * 64 + f_loc] = make_float2(0.0f, 0.0f);
        } else {
            const float2 Pp = P[((size_t)b * NBLK + tile) * FF + f];
            const float* xt = x + ((size_t)b * LL + (size_t)tile * 16) * FF + f;
            float cs = 0.0f, cs2 = 0.0f;
#pragma unroll
            for (int u = 0; u < 16; ++u) {
                const float v = sani(xt[(size_t)u * FF]);
                if (u == 0) { cs = v; cs2 = __fmul_rn(v, v); }
                else { cs = __fadd_rn(cs, v); cs2 = __fadd_rn(cs2, __fmul_rn(v, v)); }
                V2[(k * 16 + u) * 64 + f_loc] =
                    make_float2(__fadd_rn(cs, Pp.x), __fadd_rn(cs2, Pp.y));
            }
        }
    }
    __syncthreads();

    // softmax over 3 weights (uniform)
    const float w0 = w[0], w1 = w[1], w2 = w[2];
    const float mx = fmaxf(w0, fmaxf(w1, w2));
    const float e0 = expf(w0 - mx), e1 = expf(w1 - mx), e2 = expf(w2 - mx);
    const float s  = e0 + e1 + e2;
    const float ws0 = e0 / s, ws1 = e1 / s, ws2 = e2 / s;

    const int kt = tid >> 6, f_loc = tid & 63;
    const int f = fh * 64 + f_loc;
    const int tile = tq * 4 + kt;
    const float* xc0 = x   + ((size_t)b * LL + (size_t)tile * 16) * FF + f;
    float*       oc0 = out + ((size_t)b * LL + (size_t)tile * 16) * FF + f;

    auto PV = [&](int j) -> float2 {
        if (j <= 0) return make_float2(0.0f, 0.0f);
        const int idx = (j > LL ? LL : j) - 1;
        return V2[(idx - ls0) * 64 + f_loc];
    };

#pragma unroll
    for (int u = 0; u < 16; ++u) {
        const int l = tile * 16 + u;
        const float xc = sani(xc0[(size_t)u * FF]);
        const float g5  = (l >= 2  && l <= LL - 3)  ? ws0 : 0.0f;
        const float g10 = (l >= 5  && l <= LL - 5)  ? ws1 : 0.0f;
        const float g20 = (l >= 10 && l <= LL - 10) ? ws2 : 0.0f;
        const float2 A5  = PV(l + 3),  B5  = PV(l - 2);
        const float2 A10 = PV(l + 5),  B10 = PV(l - 5);
        const float2 A20 = PV(l + 10), B20 = PV(l - 10);
        float o;
        {   // w=5  (fast normalize: ulp-level deviation, realization untouched)
            const float mean = (A5.x - B5.x) * 0.2f;
            const float m2   = (A5.y - B5.y) * 0.2f;
            const float var  = fmaxf(m2 - mean * mean, 0.0f);
            const float inv  = rsqrtf(var + 1e-5f);
            o = g5 * ((xc - mean) * inv);
        }
        {   // w=10
            const float mean = (A10.x - B10.x) * 0.1f;
            const float m2   = (A10.y - B10.y) * 0.1f;
            const float var  = fmaxf(m2 - mean * mean, 0.0f);
            const float inv  = rsqrtf(var + 1e-5f);
            o += g10 * ((xc - mean) * inv);
        }
        {   // w=20
            const float mean = (A20.x - B20.x) * 0.05f;
            const float m2   = (A20.y - B20.y) * 0.05f;
            const float var  = fmaxf(m2 - mean * mean, 0.0f);
            const float inv  = rsqrtf(var + 1e-5f);
            o += g20 * ((xc - mean) * inv);
        }
        oc0[(size_t)u * FF] = o;
    }
}

// ---------- fallback: verified single-kernel r6 (if ws too small) ----------
__global__ __launch_bounds__(256) void fan_blocked(const float* __restrict__ x,
                                                   const float* __restrict__ w,
                                                   float* __restrict__ out) {
    __shared__ float2 V[LL];
    __shared__ float2 T0s[NBLK];
    __shared__ float2 T1[NOB];
    __shared__ float2 S2[NOB];
    const int col = blockIdx.x;
    const int f   = col & (FF - 1);
    const int b   = col >> 7;
    const int tid = (int)threadIdx.x;
    const float* xcol = x   + (size_t)b * LL * FF + f;
    float*       ocol = out + (size_t)b * LL * FF + f;
    for (int l = tid; l < LL; l += 256) {
        const float v = sani(xcol[(size_t)l * FF]);
        V[l] = make_float2(v, __fmul_rn(v, v));
    }
    __syncthreads();
    {
        const int base = tid * BASE;
        float cs = V[base].x, cs2 = V[base].y;
        for (int u = 1; u < BASE; ++u) {
            const float2 e = V[base + u];
            cs = __fadd_rn(cs, e.x); cs2 = __fadd_rn(cs2, e.y);
            V[base + u] = make_float2(cs, cs2);
        }
        T0s[tid] = make_float2(cs, cs2);
    }
    __syncthreads();
    if (tid < NOB) {
        const int base = tid * BASE;
        float cs = T0s[base].x, cs2 = T0s[base].y;
        for (int u = 1; u < BASE; ++u) {
            const float2 e = T0s[base + u];
            cs = __fadd_rn(cs, e.x); cs2 = __fadd_rn(cs2, e.y);
            T0s[base + u] = make_float2(cs, cs2);
        }
        T1[tid] = make_float2(cs, cs2);
    }
    __syncthreads();
    if (tid == 0) {
        float cs = T1[0].x, cs2 = T1[0].y;
        S2[0] = T1[0];
        for (int o = 1; o < NOB; ++o) {
            cs = __fadd_rn(cs, T1[o].x); cs2 = __fadd_rn(cs2, T1[o].y);
            S2[o] = make_float2(cs, cs2);
        }
    }
    __syncthreads();
    {
        const int blk = tid;
        if (blk > 0) {
            const int B = blk - 1, ob = B >> 4;
            float2 Pp = T0s[B];
            if (ob > 0) {
                const float2 s2 = S2[ob - 1];
                Pp = make_float2(__fadd_rn(Pp.x, s2.x), __fadd_rn(Pp.y, s2.y));
            }
            const int base = blk * BASE;
            for (int u = 0; u < BASE; ++u) {
                const float2 sv = V[base + u];
                V[base + u] = make_float2(__fadd_rn(sv.x, Pp.x), __fadd_rn(sv.y, Pp.y));
            }
        }
    }
    __syncthreads();
    const float w0 = w[0], w1 = w[1], w2 = w[2];
    const float mx = fmaxf(w0, fmaxf(w1, w2));
    const float e0 = expf(w0 - mx), e1 = expf(w1 - mx), e2 = expf(w2 - mx);
    const float s  = e0 + e1 + e2;
    const float ws0 = e0 / s, ws1 = e1 / s, ws2 = e2 / s;
    auto PV = [&](int j) -> float2 {
        if (j <= 0) return make_float2(0.0f, 0.0f);
        int idx = j - 1; if (idx > LL - 1) idx = LL - 1;
        return V[idx];
    };
    for (int l = tid; l < LL; l += 256) {
        const float xc = sani(xcol[(size_t)l * FF]);
        const float2 A5 = PV(l + 3), B5 = PV(l - 2);
        const float2 A10 = PV(l + 5), B10 = PV(l - 5);
        const float2 A20 = PV(l + 10), B20 = PV(l - 10);
        const float g5  = (l >= 2  && l <= LL - 3)  ? ws0 : 0.0f;
        const float g10 = (l >= 5  && l <= LL - 5)  ? ws1 : 0.0f;
        const float g20 = (l >= 10 && l <= LL - 10) ? ws2 : 0.0f;
        float o;
        {
            const float mean = (A5.x - B5.x) * 0.2f;
            const float m2   = (A5.y - B5.y) * 0.2f;
            const float var  = fmaxf(m2 - mean * mean, 0.0f);
            o = g5 * ((xc - mean) * rsqrtf(var + 1e-5f));
        }
        {
            const float mean = (A10.x - B10.x) * 0.1f;
            const float m2   = (A10.y - B10.y) * 0.1f;
            const float var  = fmaxf(m2 - mean * mean, 0.0f);
            o += g10 * ((xc - mean) * rsqrtf(var + 1e-5f));
        }
        {
            const float mean = (A20.x - B20.x) * 0.05f;
            const float m2   = (A20.y - B20.y) * 0.05f;
            const float var  = fmaxf(m2 - mean * mean, 0.0f);
            o += g20 * ((xc - mean) * rsqrtf(var + 1e-5f));
        }
        ocol[(size_t)l * FF] = o;
    }
}

extern "C" void kernel_launch(void* const* d_in, const int* in_sizes, int n_in,
                              void* d_out, int out_size, void* d_ws, size_t ws_size,
                              hipStream_t stream) {
    const float* x = (const float*)d_in[0];
    const float* w = (const float*)d_in[1];
    float* out     = (float*)d_out;

    const size_t t0_bytes = (size_t)NB * NBLK * FF * sizeof(float2);   // 8 MiB
    if (ws_size >= 2 * t0_bytes) {
        float2* T0 = (float2*)d_ws;
        float2* P  = (float2*)((char*)d_ws + t0_bytes);
        k_tiles <<<dim3(NB * 128), dim3(256), 0, stream>>>(x, T0);
        k_prefix<<<dim3(NB * 2),   dim3(64),  0, stream>>>(T0, P);
        k_win   <<<dim3(NB * 64 * 2), dim3(256), 0, stream>>>(x, w, P, out);
    } else {
        fan_blocked<<<dim3(NB * FF), dim3(256), 0, stream>>>(x, w, out);
    }
}